// Round 2
// baseline (140.725 us; speedup 1.0000x reference)
//
#include <hip/hip_runtime.h>
#include <math.h>

#define B_SZ 256
#define N_SZ 1024
#define D_MODEL 128
#define NUM_CLASSES 32
#define PPB 256          // points per block in the store kernel

// exp(-ETA*d^2) = 2^(d^2 * -ETA*log2(e));  -4 * 1.4426950408889634
#define K_EXP (-5.770780163555854f)
// cos(pi*rc/RC) with v_cos (revolutions): arg = rc/(2*RC) = rc/12
#define K_COS (1.0f / 12.0f)

__device__ __forceinline__ void compute_prod(const float4 xv, float& r, int& c, float p[4]) {
    const float y00 = 0.28209479177387814f;  // 0.5/sqrt(pi)
    const float c1  = 0.48860251190291992f;  // sqrt(3/(4pi))
    float r2 = xv.x * xv.x + xv.y * xv.y + xv.z * xv.z;
    r = sqrtf(r2);
    c = (int)xv.w;
    float inv_r = (r > 0.0f) ? __builtin_amdgcn_rcpf(r) : 0.0f;
    float ux = xv.x * inv_r, uy = xv.y * inv_r, uz = xv.z * inv_r;
    float rc = fminf(r, 6.0f);
    float env = 0.5f * __builtin_amdgcn_cosf(rc * K_COS) + 0.5f;
    float d0 = 0.0f - r, d1 = 1.5f - r, d2 = 3.0f - r, d3 = 4.5f - r;
    float rad0 = __builtin_amdgcn_exp2f(d0 * d0 * K_EXP);
    float rad1 = __builtin_amdgcn_exp2f(d1 * d1 * K_EXP);
    float rad2 = __builtin_amdgcn_exp2f(d2 * d2 * K_EXP);
    float rad3 = __builtin_amdgcn_exp2f(d3 * d3 * K_EXP);
    p[0] = y00 * rad0 * env;
    p[1] = c1 * uy * rad1 * env;
    p[2] = c1 * uz * rad2 * env;
    p[3] = c1 * ux * rad3 * env;
}

// Kernel 1: per-batch feature norms. One block per batch, one point per thread.
// Writes invn[b][128] = 1/max(||pos_f||, 1e-12) to workspace.
__global__ __launch_bounds__(1024) void ape_norm_kernel(const float* __restrict__ x,
                                                        float* __restrict__ invn_g) {
    __shared__ float nsq[D_MODEL];
    const int b = blockIdx.x;
    const int t = threadIdx.x;
    if (t < D_MODEL) nsq[t] = 0.0f;
    __syncthreads();

    float4 xv = ((const float4*)x)[(size_t)b * N_SZ + t];
    float r; int c; float p[4];
    compute_prod(xv, r, c, p);
    if (r > 0.0f) {
        atomicAdd(&nsq[0 * NUM_CLASSES + c], p[0] * p[0]);
        atomicAdd(&nsq[1 * NUM_CLASSES + c], p[1] * p[1]);
        atomicAdd(&nsq[2 * NUM_CLASSES + c], p[2] * p[2]);
        atomicAdd(&nsq[3 * NUM_CLASSES + c], p[3] * p[3]);
    }
    __syncthreads();

    if (t < D_MODEL) {
        invn_g[(size_t)b * D_MODEL + t] =
            __builtin_amdgcn_rcpf(fmaxf(sqrtf(nsq[t]), 1e-12f));
    }
}

// Kernel 2: streaming normalize + LayerNorm + expand + store.
// 1024 blocks x 256 threads: block handles PPB=256 points of one batch.
// Phase A: one point per thread (recompute prod — input is tiny), LN stats -> LDS.
// Phase B: 32 lanes per point; each wave stores 1024 contiguous bytes,
//          consecutive waves/iterations cover consecutive points.
__global__ __launch_bounds__(256) void ape_store_kernel(const float* __restrict__ x,
                                                        const float* __restrict__ invn_g,
                                                        float* __restrict__ out) {
    __shared__ float invn[D_MODEL];
    __shared__ float4 samb[PPB];   // per-point (a-mean)/std at the 4 hot features
    __shared__ float2 sbc[PPB];    // per-point {bneg, cls-as-bits}

    const int b  = blockIdx.x >> 2;          // N_SZ/PPB == 4 blocks per batch
    const int n0 = (blockIdx.x & 3) << 8;    // base point within batch
    const int t  = threadIdx.x;

    if (t < D_MODEL) invn[t] = invn_g[(size_t)b * D_MODEL + t];
    __syncthreads();

    // Phase A: one point per thread
    {
        const int n = n0 + t;
        float4 xv = ((const float4*)x)[(size_t)b * N_SZ + n];
        float r; int c; float p[4];
        compute_prod(xv, r, c, p);
        if (r <= 0.0f) { p[0] = p[1] = p[2] = p[3] = 0.0f; }
        float pn0 = p[0] * invn[0 * NUM_CLASSES + c];
        float pn1 = p[1] * invn[1 * NUM_CLASSES + c];
        float pn2 = p[2] * invn[2 * NUM_CLASSES + c];
        float pn3 = p[3] * invn[3 * NUM_CLASSES + c];
        float sum = pn0 + pn1 + pn2 + pn3;
        float mean = sum * (1.0f / 128.0f);
        float sumsq = pn0 * pn0 + pn1 * pn1 + pn2 * pn2 + pn3 * pn3;
        float var = fmaxf((sumsq - 128.0f * mean * mean) * (1.0f / 127.0f), 0.0f);
        float inv_std = __builtin_amdgcn_rcpf(sqrtf(var) + 1e-6f);
        float bneg = -mean * inv_std;
        samb[t] = make_float4(pn0 * inv_std + bneg,
                              pn1 * inv_std + bneg,
                              pn2 * inv_std + bneg,
                              pn3 * inv_std + bneg);
        sbc[t] = make_float2(bneg, __int_as_float(c));
    }
    __syncthreads();

    // Phase B: 32 lanes per point; 8 points per iteration (4 KB contiguous per block-iter)
    {
        const int lane = t & 31;
        const int grp  = t >> 5;          // 0..7
        const int qsel = lane >> 3;       // radial block owned by this lane
        const int m    = (lane & 7) * 4;  // class offset within the 32-class block
        const float* samb_f = (const float*)samb;
        float4* op = (float4*)out + ((size_t)b * N_SZ + n0 + grp) * 32 + lane;
#pragma unroll
        for (int k = 0; k < PPB / 8; ++k) {
            const int n = (k << 3) + grp;
            const float a   = samb_f[(n << 2) + qsel];
            const float2 bc = sbc[n];
            const float bneg = bc.x;
            const int   c    = __float_as_int(bc.y);
            float4 o;
            o.x = (c == m + 0) ? a : bneg;
            o.y = (c == m + 1) ? a : bneg;
            o.z = (c == m + 2) ? a : bneg;
            o.w = (c == m + 3) ? a : bneg;
            op[(size_t)k * (8 * 32)] = o;
        }
    }
}

extern "C" void kernel_launch(void* const* d_in, const int* in_sizes, int n_in,
                              void* d_out, int out_size, void* d_ws, size_t ws_size,
                              hipStream_t stream) {
    const float* x = (const float*)d_in[0];
    float* out = (float*)d_out;
    float* invn_g = (float*)d_ws;   // B_SZ * D_MODEL floats = 128 KB
    ape_norm_kernel<<<B_SZ, 1024, 0, stream>>>(x, invn_g);
    ape_store_kernel<<<B_SZ * (N_SZ / PPB), 256, 0, stream>>>(x, invn_g, out);
}